// Round 4
// baseline (150.103 us; speedup 1.0000x reference)
//
#include <hip/hip_runtime.h>

// SqueezeExcitation: x[32,256,64,64] f32, W1[64,256], b1[64], W2[256,64], b2[256]
// y = x * hardsigmoid( relu( mean_hw(x) @ W1^T + b1 ) @ W2^T + b2 )
// conv1x1 is linear => mean-then-matvec == matvec-then-mean. TWO kernels:
//   K1: per-(b,c) spatial mean m[b,c]               (reads x, 128 MiB)
//   K2: per-(b,c) block computes the gate scalar REDUNDANTLY from m (tiny,
//       W1/W2 are L1/L2-resident), then y = x*g with nontemporal stores.
// Round-2 lesson: NO cross-block atomics/fences (contended device-scope
// atomics serialize at ~50ns; 8192 of them = 448us). Redundant compute is free.

#define SE_B  32
#define SE_C  256
#define SE_SQ 64
#define SE_HW 4096   // 64*64

typedef float f32x4 __attribute__((ext_vector_type(4)));

__device__ __forceinline__ float hsig(float v) {
    return fminf(fmaxf(v * (1.0f / 6.0f) + 0.5f, 0.0f), 1.0f);
}

// ---------------- Kernel 1: per-(b,c) spatial mean --------------------------
__global__ __launch_bounds__(256) void se_mean_kernel(
    const float* __restrict__ x, float* __restrict__ m) {
    const int bc = blockIdx.x;                       // [0, B*C)
    const int t  = threadIdx.x;
    const f32x4* xv = reinterpret_cast<const f32x4*>(x) + (size_t)bc * (SE_HW / 4);

    float s = 0.0f;
#pragma unroll
    for (int k = 0; k < 4; ++k) {
        f32x4 v = xv[t + 256 * k];
        s += (v.x + v.y) + (v.z + v.w);
    }
#pragma unroll
    for (int off = 32; off > 0; off >>= 1) s += __shfl_down(s, off);

    __shared__ float wsum[4];
    if ((t & 63) == 0) wsum[t >> 6] = s;
    __syncthreads();
    if (t == 0) m[bc] = (wsum[0] + wsum[1] + wsum[2] + wsum[3]) * (1.0f / SE_HW);
}

// ---------------- Kernel 2: gate (redundant per block) + scale --------------
// one block per (b,c). Pre-work: this block computes g[b,c] itself from m[b,:]
// (deterministic fixed FP order, identical for every block of batch b).
__global__ __launch_bounds__(256) void se_gate_scale_kernel(
    const float* __restrict__ x, const float* __restrict__ m,
    const float* __restrict__ W1, const float* __restrict__ b1,
    const float* __restrict__ W2, const float* __restrict__ b2,
    float* __restrict__ y) {
    const int bc = blockIdx.x;
    const int b  = bc >> 8;
    const int c  = bc & 255;
    const int t  = threadIdx.x;

    __shared__ float ss[SE_SQ];
    __shared__ float sg;

    // ---- step 1: s[o] = relu(b1[o] + sum_k W1[o,k] * m[b,k]) --------------
    // thread t handles o = t>>2 over k-quarter q = t&3 (64 MACs), then the
    // 4 partials reduce across adjacent lanes (same wave).
    {
        const int o = t >> 2;
        const int q = t & 3;
        const float* w  = W1 + o * SE_C + q * 64;
        const float* mb = m  + b * SE_C + q * 64;
        float acc = 0.0f;
#pragma unroll 16
        for (int k = 0; k < 64; ++k) acc = fmaf(w[k], mb[k], acc);
        acc += __shfl_xor(acc, 1);
        acc += __shfl_xor(acc, 2);
        if (q == 0) ss[o] = fmaxf(acc + b1[o], 0.0f);
    }
    __syncthreads();

    // ---- step 2: g = hardsigmoid(b2[c] + sum_o W2[c,o] * s[o]) ------------
    if (t < SE_SQ) {
        float p = W2[c * SE_SQ + t] * ss[t];
#pragma unroll
        for (int off = 32; off > 0; off >>= 1) p += __shfl_down(p, off);
        if (t == 0) sg = hsig(p + b2[c]);
    }
    __syncthreads();
    const float g = sg;

    // ---- step 3: y = x * g, nontemporal stores ----------------------------
    const f32x4* xv = reinterpret_cast<const f32x4*>(x) + (size_t)bc * (SE_HW / 4);
    f32x4*       yv = reinterpret_cast<f32x4*>(y)       + (size_t)bc * (SE_HW / 4);
#pragma unroll
    for (int k = 0; k < 4; ++k) {
        f32x4 v = xv[t + 256 * k];
        v *= g;
        __builtin_nontemporal_store(v, &yv[t + 256 * k]);
    }
}

extern "C" void kernel_launch(void* const* d_in, const int* in_sizes, int n_in,
                              void* d_out, int out_size, void* d_ws, size_t ws_size,
                              hipStream_t stream) {
    const float* x  = (const float*)d_in[0];
    const float* W1 = (const float*)d_in[1];
    const float* b1 = (const float*)d_in[2];
    const float* W2 = (const float*)d_in[3];
    const float* b2 = (const float*)d_in[4];
    float* y = (float*)d_out;

    float* m = (float*)d_ws;               // B*C floats

    se_mean_kernel<<<SE_B * SE_C, 256, 0, stream>>>(x, m);
    se_gate_scale_kernel<<<SE_B * SE_C, 256, 0, stream>>>(x, m, W1, b1, W2, b2, y);
}

// Round 5
// 69.936 us; speedup vs baseline: 2.1463x; 2.1463x over previous
//
#include <hip/hip_runtime.h>

// SqueezeExcitation: x[32,256,64,64] f32, W1[64,256], b1[64], W2[256,64], b2[256]
// y = x * hardsigmoid( relu( mean_hw(x) @ W1^T + b1 ) @ W2^T + b2 )
// conv1x1 linear => mean-then-matvec == matvec-then-mean. TWO kernels:
//   K1: per-(b,c) spatial mean m[b,c]                    (reads x, 128 MiB)
//   K2: fat blocks (1024 thr, batch x 16-channel chunk): compute gate
//       redundantly per block with COALESCED W1/W2 reads (64 KiB W1 vs
//       256 KiB payload = 25% overhead, vs round-4's 400% uncoalesced),
//       then stream y = x*g with nontemporal stores.
// Round-2 lesson: no cross-block atomics/fences (contended device atomics
// serialize ~50ns each). Round-4 lesson: per-block redundant work must be
// coalesced AND small vs payload.

#define SE_B  32
#define SE_C  256
#define SE_SQ 64
#define SE_HW 4096   // 64*64
#define CHUNK 16     // channels per fused block

typedef float f32x4 __attribute__((ext_vector_type(4)));

__device__ __forceinline__ float hsig(float v) {
    return fminf(fmaxf(v * (1.0f / 6.0f) + 0.5f, 0.0f), 1.0f);
}

// ---------------- Kernel 1: per-(b,c) spatial mean --------------------------
__global__ __launch_bounds__(256) void se_mean_kernel(
    const float* __restrict__ x, float* __restrict__ m) {
    const int bc = blockIdx.x;                       // [0, B*C)
    const int t  = threadIdx.x;
    const f32x4* xv = reinterpret_cast<const f32x4*>(x) + (size_t)bc * (SE_HW / 4);

    float s = 0.0f;
#pragma unroll
    for (int k = 0; k < 4; ++k) {
        f32x4 v = xv[t + 256 * k];
        s += (v.x + v.y) + (v.z + v.w);
    }
#pragma unroll
    for (int off = 32; off > 0; off >>= 1) s += __shfl_down(s, off);

    __shared__ float wsum[4];
    if ((t & 63) == 0) wsum[t >> 6] = s;
    __syncthreads();
    if (t == 0) m[bc] = (wsum[0] + wsum[1] + wsum[2] + wsum[3]) * (1.0f / SE_HW);
}

// ---------------- Kernel 2: fused gate + scale (fat blocks) -----------------
// grid = 32 batches * 16 chunks = 512 blocks of 1024 threads (16 waves).
// Each block: compute s[b,:] (W1 read coalesced, f32x4 row per wave-op),
// gates for its 16 channels, then stream 16 x 16 KiB of x -> y.
__global__ __launch_bounds__(1024, 8) void se_gate_scale_kernel(
    const float* __restrict__ x, const float* __restrict__ m,
    const float* __restrict__ W1, const float* __restrict__ b1,
    const float* __restrict__ W2, const float* __restrict__ b2,
    float* __restrict__ y) {
    const int b     = blockIdx.x >> 4;
    const int chunk = blockIdx.x & 15;
    const int c0    = chunk * CHUNK;
    const int t     = threadIdx.x;
    const int wave  = t >> 6;            // 0..15
    const int lane  = t & 63;

    __shared__ f32x4 m4_lds[SE_C / 4];   // m[b,:] as 64 float4
    __shared__ float s_lds[SE_SQ];
    __shared__ float g_lds[CHUNK];

    // ---- stage m[b,:] (1 KiB, coalesced) ----------------------------------
    if (t < SE_C / 4)
        m4_lds[t] = reinterpret_cast<const f32x4*>(m + b * SE_C)[t];
    __syncthreads();

    // ---- s[o] = relu(b1[o] + W1[o,:] . m[b,:]), wave w owns o = 4w..4w+3 --
    const f32x4* W1v = reinterpret_cast<const f32x4*>(W1);
    const f32x4 mv = m4_lds[lane];
#pragma unroll
    for (int i = 0; i < 4; ++i) {
        const int o = wave * 4 + i;
        f32x4 w4 = W1v[o * 64 + lane];               // coalesced: whole row/wave
        float p = w4.x * mv.x;
        p = fmaf(w4.y, mv.y, p);
        p = fmaf(w4.z, mv.z, p);
        p = fmaf(w4.w, mv.w, p);
#pragma unroll
        for (int off = 1; off < 64; off <<= 1) p += __shfl_xor(p, off);
        if (lane == 0) s_lds[o] = fmaxf(p + b1[o], 0.0f);
    }
    __syncthreads();

    // ---- gate for channel c0+wave (wave j owns channel j of the chunk) ----
    {
        const int c = c0 + wave;                     // CHUNK == 16 waves
        float p = W2[c * SE_SQ + lane] * s_lds[lane];
#pragma unroll
        for (int off = 1; off < 64; off <<= 1) p += __shfl_xor(p, off);
        if (lane == 0) g_lds[wave] = hsig(p + b2[c]);
    }
    __syncthreads();

    // ---- stream: y = x * g, one 16 KiB channel per round ------------------
    const size_t base = ((size_t)b * SE_C + c0) * (SE_HW / 4);
    const f32x4* xv = reinterpret_cast<const f32x4*>(x) + base;
    f32x4*       yv = reinterpret_cast<f32x4*>(y)       + base;
#pragma unroll 4
    for (int j = 0; j < CHUNK; ++j) {
        const float g = g_lds[j];
        f32x4 v = xv[j * (SE_HW / 4) + t];
        v *= g;
        __builtin_nontemporal_store(v, &yv[j * (SE_HW / 4) + t]);
    }
}

extern "C" void kernel_launch(void* const* d_in, const int* in_sizes, int n_in,
                              void* d_out, int out_size, void* d_ws, size_t ws_size,
                              hipStream_t stream) {
    const float* x  = (const float*)d_in[0];
    const float* W1 = (const float*)d_in[1];
    const float* b1 = (const float*)d_in[2];
    const float* W2 = (const float*)d_in[3];
    const float* b2 = (const float*)d_in[4];
    float* y = (float*)d_out;

    float* m = (float*)d_ws;               // B*C floats

    se_mean_kernel<<<SE_B * SE_C, 256, 0, stream>>>(x, m);
    se_gate_scale_kernel<<<SE_B * (SE_C / CHUNK), 1024, 0, stream>>>(
        x, m, W1, b1, W2, b2, y);
}

// Round 6
// 69.369 us; speedup vs baseline: 2.1638x; 1.0082x over previous
//
#include <hip/hip_runtime.h>

// SqueezeExcitation: x[32,256,64,64] f32, W1[64,256], b1[64], W2[256,64], b2[256]
// y = x * hardsigmoid( relu( mean_hw(x) @ W1^T + b1 ) @ W2^T + b2 )
// conv1x1 linear => mean-then-matvec == matvec-then-mean. TWO kernels:
//   K1: per-(b,c) spatial mean m[b,c]                    (reads x, 128 MiB)
//   K2: fat blocks (1024 thr, batch x 16-channel chunk): redundant per-block
//       gate (coalesced W1/W2), then y = x*g with nontemporal stores.
//       K2 traverses x in REVERSE block order: K1 read x ascending, so the
//       MRU lines are at the END of x; reverse re-read makes every line hit
//       L3 under LRU (128 MiB x fits the 256 MiB Infinity Cache).
// Round-2 lesson: no cross-block atomics/fences. Round-4 lesson: redundant
// per-block work must be coalesced and small vs payload; x re-read was only
// ~50% L3-resident with same-order traversal (FETCH 64/128 MiB).

#define SE_B  32
#define SE_C  256
#define SE_SQ 64
#define SE_HW 4096   // 64*64
#define CHUNK 16     // channels per fused block

typedef float f32x4 __attribute__((ext_vector_type(4)));

__device__ __forceinline__ float hsig(float v) {
    return fminf(fmaxf(v * (1.0f / 6.0f) + 0.5f, 0.0f), 1.0f);
}

// ---------------- Kernel 1: per-(b,c) spatial mean --------------------------
__global__ __launch_bounds__(256) void se_mean_kernel(
    const float* __restrict__ x, float* __restrict__ m) {
    const int bc = blockIdx.x;                       // [0, B*C)
    const int t  = threadIdx.x;
    const f32x4* xv = reinterpret_cast<const f32x4*>(x) + (size_t)bc * (SE_HW / 4);

    float s = 0.0f;
#pragma unroll
    for (int k = 0; k < 4; ++k) {
        f32x4 v = xv[t + 256 * k];
        s += (v.x + v.y) + (v.z + v.w);
    }
#pragma unroll
    for (int off = 32; off > 0; off >>= 1) s += __shfl_down(s, off);

    __shared__ float wsum[4];
    if ((t & 63) == 0) wsum[t >> 6] = s;
    __syncthreads();
    if (t == 0) m[bc] = (wsum[0] + wsum[1] + wsum[2] + wsum[3]) * (1.0f / SE_HW);
}

// ---------------- Kernel 2: fused gate + scale (fat blocks, reversed) -------
// grid = 32 batches * 16 chunks = 512 blocks of 1024 threads (16 waves).
__global__ __launch_bounds__(1024, 8) void se_gate_scale_kernel(
    const float* __restrict__ x, const float* __restrict__ m,
    const float* __restrict__ W1, const float* __restrict__ b1,
    const float* __restrict__ W2, const float* __restrict__ b2,
    float* __restrict__ y) {
    // reverse traversal: first-dispatched blocks take the HIGHEST addresses
    const int blk   = (SE_B * (SE_C / CHUNK) - 1) - blockIdx.x;
    const int b     = blk >> 4;
    const int chunk = blk & 15;
    const int c0    = chunk * CHUNK;
    const int t     = threadIdx.x;
    const int wave  = t >> 6;            // 0..15
    const int lane  = t & 63;

    __shared__ f32x4 m4_lds[SE_C / 4];   // m[b,:] as 64 float4
    __shared__ float s_lds[SE_SQ];
    __shared__ float g_lds[CHUNK];

    // ---- stage m[b,:] (1 KiB, coalesced) ----------------------------------
    if (t < SE_C / 4)
        m4_lds[t] = reinterpret_cast<const f32x4*>(m + b * SE_C)[t];
    __syncthreads();

    // ---- s[o] = relu(b1[o] + W1[o,:] . m[b,:]), wave w owns o = 4w..4w+3 --
    const f32x4* W1v = reinterpret_cast<const f32x4*>(W1);
    const f32x4 mv = m4_lds[lane];
#pragma unroll
    for (int i = 0; i < 4; ++i) {
        const int o = wave * 4 + i;
        f32x4 w4 = W1v[o * 64 + lane];               // coalesced: whole row/wave
        float p = w4.x * mv.x;
        p = fmaf(w4.y, mv.y, p);
        p = fmaf(w4.z, mv.z, p);
        p = fmaf(w4.w, mv.w, p);
#pragma unroll
        for (int off = 1; off < 64; off <<= 1) p += __shfl_xor(p, off);
        if (lane == 0) s_lds[o] = fmaxf(p + b1[o], 0.0f);
    }
    __syncthreads();

    // ---- gate for channel c0+wave (wave j owns channel j of the chunk) ----
    {
        const int c = c0 + wave;                     // CHUNK == 16 waves
        float p = W2[c * SE_SQ + lane] * s_lds[lane];
#pragma unroll
        for (int off = 1; off < 64; off <<= 1) p += __shfl_xor(p, off);
        if (lane == 0) g_lds[wave] = hsig(p + b2[c]);
    }
    __syncthreads();

    // ---- stream: y = x * g, one 16 KiB channel per round, high->low -------
    const size_t base = ((size_t)b * SE_C + c0) * (SE_HW / 4);
    const f32x4* xv = reinterpret_cast<const f32x4*>(x) + base;
    f32x4*       yv = reinterpret_cast<f32x4*>(y)       + base;
#pragma unroll 4
    for (int jj = 0; jj < CHUNK; ++jj) {
        const int j = CHUNK - 1 - jj;                // reversed within block too
        const float g = g_lds[j];
        f32x4 v = xv[j * (SE_HW / 4) + t];
        v *= g;
        __builtin_nontemporal_store(v, &yv[j * (SE_HW / 4) + t]);
    }
}

extern "C" void kernel_launch(void* const* d_in, const int* in_sizes, int n_in,
                              void* d_out, int out_size, void* d_ws, size_t ws_size,
                              hipStream_t stream) {
    const float* x  = (const float*)d_in[0];
    const float* W1 = (const float*)d_in[1];
    const float* b1 = (const float*)d_in[2];
    const float* W2 = (const float*)d_in[3];
    const float* b2 = (const float*)d_in[4];
    float* y = (float*)d_out;

    float* m = (float*)d_ws;               // B*C floats

    se_mean_kernel<<<SE_B * SE_C, 256, 0, stream>>>(x, m);
    se_gate_scale_kernel<<<SE_B * (SE_C / CHUNK), 1024, 0, stream>>>(
        x, m, W1, b1, W2, b2, y);
}